// Round 1
// baseline (442.284 us; speedup 1.0000x reference)
//
#include <hip/hip_runtime.h>

#define NUM_C 19
#define HW_SHIFT 19                 // H*W = 512*1024 = 2^19
#define HW (1 << HW_SHIFT)          // 524288
#define NPIX (8 * HW)               // B*H*W = 4194304
#define NGROUPS (NPIX / 4)          // float4 groups = 1048576

// ws layout: ws[0..18] = per-class sum of nll, ws[19..37] = per-class counts
__global__ __launch_bounds__(256) void ifl_main(const float* __restrict__ x,
                                                const int* __restrict__ tgt,
                                                float* __restrict__ ws) {
    __shared__ float red[2 * NUM_C];
    if (threadIdx.x < 2 * NUM_C) red[threadIdx.x] = 0.0f;
    __syncthreads();

    float acc[NUM_C];
    float cnt[NUM_C];
#pragma unroll
    for (int c = 0; c < NUM_C; ++c) { acc[c] = 0.0f; cnt[c] = 0.0f; }

    const int tid = blockIdx.x * blockDim.x + threadIdx.x;
    const int nthreads = gridDim.x * blockDim.x;

    union F4 { float4 q; float f[4]; };
    union I4 { int4 q; int i[4]; };

    for (int g = tid; g < NGROUPS; g += nthreads) {
        const int p = g << 2;                 // pixel index (4-aligned, never crosses batch)
        const int b = p >> HW_SHIFT;          // batch
        const int r = p & (HW - 1);           // h*W + w
        const float4* base4 =
            reinterpret_cast<const float4*>(x + ((size_t)(b * NUM_C) << HW_SHIFT) + r);

        F4 v[NUM_C];
#pragma unroll
        for (int c = 0; c < NUM_C; ++c) v[c].q = base4[(size_t)c << (HW_SHIFT - 2)];

        I4 tt;
        tt.q = *reinterpret_cast<const int4*>(tgt + p);

#pragma unroll
        for (int k = 0; k < 4; ++k) {
            const int tg = tt.i[k];
            float m = v[0].f[k];
#pragma unroll
            for (int c = 1; c < NUM_C; ++c) m = fmaxf(m, v[c].f[k]);
            float s = 0.0f;
#pragma unroll
            for (int c = 0; c < NUM_C; ++c) s += __expf(v[c].f[k] - m);
            float xt = v[0].f[k];
#pragma unroll
            for (int c = 1; c < NUM_C; ++c) xt = (tg == c) ? v[c].f[k] : xt;
            const float nll = m + __logf(s) - xt;
#pragma unroll
            for (int c = 0; c < NUM_C; ++c) {
                const bool h = (tg == c);
                acc[c] += h ? nll : 0.0f;
                cnt[c] += h ? 1.0f : 0.0f;
            }
        }
    }

    // wave(64)-level shuffle reduction, then per-block LDS reduction
#pragma unroll
    for (int c = 0; c < NUM_C; ++c) {
        float a = acc[c];
        float n = cnt[c];
#pragma unroll
        for (int off = 32; off > 0; off >>= 1) {
            a += __shfl_down(a, off, 64);
            n += __shfl_down(n, off, 64);
        }
        if ((threadIdx.x & 63) == 0) {
            atomicAdd(&red[c], a);
            atomicAdd(&red[NUM_C + c], n);
        }
    }
    __syncthreads();

    // one global atomic per class-value per block
    if (threadIdx.x < 2 * NUM_C) atomicAdd(&ws[threadIdx.x], red[threadIdx.x]);
}

__global__ void ifl_final(const float* __restrict__ ws, float* __restrict__ out) {
    if (threadIdx.x == 0) {
        float num = 0.0f, den = 0.0f;
#pragma unroll
        for (int c = 0; c < NUM_C; ++c) {
            const float cn = ws[NUM_C + c];
            const float inv = (cn > 0.0f) ? (1.0f / fmaxf(cn, 1.0f)) : 1.0f;
            num += inv * ws[c];
            den += inv * cn;
        }
        out[0] = num / den;
    }
}

extern "C" void kernel_launch(void* const* d_in, const int* in_sizes, int n_in,
                              void* d_out, int out_size, void* d_ws, size_t ws_size,
                              hipStream_t stream) {
    const float* x = (const float*)d_in[0];
    const int* tgt = (const int*)d_in[1];
    float* ws = (float*)d_ws;
    float* out = (float*)d_out;

    // d_ws is re-poisoned to 0xAA before every call — zero the 38 accumulators
    hipMemsetAsync(ws, 0, 2 * NUM_C * sizeof(float), stream);

    ifl_main<<<2048, 256, 0, stream>>>(x, tgt, ws);
    ifl_final<<<1, 64, 0, stream>>>(ws, out);
}